// Round 7
// baseline (217.017 us; speedup 1.0000x reference)
//
#include <hip/hip_runtime.h>
#include <stdint.h>

// Problem constants (from reference): B=16384, F=32, D=64, H=2*D=128.
#define B_SZ 16384
#define F_SZ 32
#define D_SZ 64
#define H_SZ 128

typedef __attribute__((ext_vector_type(8))) short  short8;   // 8 x bf16 MFMA frag
typedef __attribute__((ext_vector_type(4))) float  float4v;
typedef __attribute__((ext_vector_type(4))) unsigned int uint4v;

// round-half-up f32->bf16, pack (lo -> bits[15:0], hi -> bits[31:16])
__device__ __forceinline__ unsigned int pkbf(float lo, float hi) {
  unsigned int ulo = __builtin_bit_cast(unsigned int, lo) + 0x8000u;
  unsigned int uhi = __builtin_bit_cast(unsigned int, hi) + 0x8000u;
  return __builtin_amdgcn_perm(uhi, ulo, 0x07060302u);
}

// Kernel 1: W1 [F][D][H] f32 -> w1t [F][H][D] bf16 (A-fragment order), and
// pack {b1,w2} per h into one u32 (b1 hi16, w2 lo16).
__global__ __launch_bounds__(256) void ContMlp_prep(
    const float* __restrict__ W1, const float* __restrict__ b1,
    const float* __restrict__ W2, unsigned short* __restrict__ w1t,
    unsigned int* __restrict__ bw) {
  const int f  = blockIdx.x >> 2;
  const int hq = blockIdx.x & 3;
  const int h0 = hq * 32;
  const int t  = threadIdx.x;
  __shared__ float lds[D_SZ][33];
  const float* w1f = W1 + (size_t)f * (D_SZ * H_SZ);
#pragma unroll
  for (int i = 0; i < 8; ++i) {
    int idx = t + 256 * i;
    int d = idx >> 5, hh = idx & 31;
    lds[d][hh] = w1f[d * H_SZ + h0 + hh];
  }
  __syncthreads();
  unsigned short* o = w1t + (size_t)f * (H_SZ * D_SZ);
#pragma unroll
  for (int i = 0; i < 8; ++i) {
    int idx = t + 256 * i;
    int hh = idx >> 6, d = idx & 63;
    unsigned int u = __builtin_bit_cast(unsigned int, lds[d][hh]) + 0x8000u;
    o[(h0 + hh) * D_SZ + d] = (unsigned short)(u >> 16);
  }
  if (hq == 0 && t < H_SZ) {
    unsigned int ub = __builtin_bit_cast(unsigned int, b1[f * H_SZ + t]) + 0x8000u;
    unsigned int uw = __builtin_bit_cast(unsigned int, W2[f * H_SZ + t]) + 0x8000u;
    bw[f * H_SZ + t] = (ub & 0xFFFF0000u) | (uw >> 16);
  }
}

// Kernel 2: main. Grid = 64 row-tiles x 32 f = 2048 blocks. Block = 2 waves
// (128 thr) x 128 rows each; 8 subtiles of 16 rows per wave.
//
// LDS = w1l 16 KB (unpadded: A-frag ds_read_b128 is a 16-lane same-address
// broadcast per quad -> conflict-free) + bwl 0.5 KB + rbuf dbuf 16 KB
// = 33.3 KB -> 4 blocks/CU -> 2 waves/EU -> 256-VGPR allocator budget
// (R1-R5 lesson: LDS-implied occupancy is what actually sets the budget).
// That budget lets A-frags (64 VGPR) + packed b1/w2 (32 VGPR) live in regs.
//
// r_ staging: global_load_lds width=16 into per-wave 4 KB halves,
// double-buffered. Waits are vmcnt(4) -- only the PREVIOUS subtile's 4 DMA
// loads are drained; the next subtile's stay in flight across the compute
// (AITER-style never-drain). In-queue order [pf_s x4, store_{s-1}, pf_{s+1} x4]
// makes vmcnt(4) also retire the y store safely. Last iter uses vmcnt(0).
__global__ __launch_bounds__(128) void ContMlp_main(
    const float* __restrict__ r_,
    const unsigned short* __restrict__ w1t, const unsigned int* __restrict__ bw,
    const float* __restrict__ b2, float* __restrict__ ydst,
    int y_fmul, int y_rmul, int y_cadd) {
  const int f    = blockIdx.x & 31;
  const int tile = blockIdx.x >> 5;            // 0..63
  const int w    = threadIdx.x >> 6;           // 0..1
  const int l    = threadIdx.x & 63;
  const int col  = l & 15;
  const int quad = l >> 4;

  __shared__ unsigned short w1l[H_SZ * D_SZ];  // 16384 B
  __shared__ unsigned int   bwl[H_SZ];         // 512 B
  __shared__ float          rbuf[2][2][1024];  // 16384 B (wave x half x 4KB)

  {  // stage weights (linear 16 KB copy) + packed bias/w2
    const uint4v* src = (const uint4v*)(w1t + (size_t)f * (H_SZ * D_SZ));
    uint4v* dst = (uint4v*)w1l;
#pragma unroll
    for (int i = 0; i < 8; ++i)
      dst[threadIdx.x + 128 * i] = src[threadIdx.x + 128 * i];
    bwl[threadIdx.x] = bw[f * H_SZ + threadIdx.x];   // 128 threads = H_SZ
  }
  __syncthreads();

  // A-fragments + {b1,w2} into registers (~150 VGPR live, budget 256).
  short8 afrag[8][2];
#pragma unroll
  for (int t = 0; t < 8; ++t)
#pragma unroll
    for (int ks = 0; ks < 2; ++ks)
      afrag[t][ks] = *(const short8*)(w1l + (col + 16 * t) * D_SZ + ks * 32 + quad * 8);
  uint4v bwreg[8];
#pragma unroll
  for (int t = 0; t < 8; ++t)
    bwreg[t] = *(const uint4v*)(bwl + 16 * t + quad * 4);
  const float b2f = b2[f];

  const int row_w0 = tile * 256 + w * 128;     // wave's first row
  // lane's staging gather base: row (row_w0+col), float offset quad*4
  const float* gl = r_ + (size_t)(row_w0 + col) * (F_SZ * D_SZ)
                       + f * D_SZ + quad * 4;

#define ISSUE(S, HALF)                                                       \
  do {                                                                       \
    const float* gs_ = gl + (size_t)(S) * 16 * (F_SZ * D_SZ);                \
    float* rb_ = &rbuf[w][HALF][0];                                          \
    _Pragma("unroll")                                                        \
    for (int i_ = 0; i_ < 4; ++i_)                                           \
      __builtin_amdgcn_global_load_lds(                                      \
          (const __attribute__((address_space(1))) void*)(gs_ + i_ * 16),    \
          (__attribute__((address_space(3))) void*)(rb_ + i_ * 256),         \
          16, 0, 0);                                                         \
  } while (0)

  ISSUE(0, 0);

#pragma unroll 1
  for (int s = 0; s < 8; ++s) {
    if (s < 7) {
      ISSUE(s + 1, (s + 1) & 1);
      __builtin_amdgcn_s_waitcnt(0x0F74);   // vmcnt(4): drain prev subtile only
    } else {
      __builtin_amdgcn_s_waitcnt(0x0F70);   // vmcnt(0): final drain
    }
    const float* rb = &rbuf[w][s & 1][0];

    // fragment read (chunk-major): chunk c at floats c*64 + col*4
    float4v f0 = *(const float4v*)(rb + (quad * 2) * 64 + col * 4);
    float4v f1 = *(const float4v*)(rb + (quad * 2 + 1) * 64 + col * 4);
    float4v f2 = *(const float4v*)(rb + (8 + quad * 2) * 64 + col * 4);
    float4v f3 = *(const float4v*)(rb + (9 + quad * 2) * 64 + col * 4);
    uint4v bq0 = {pkbf(f0.x, f0.y), pkbf(f0.z, f0.w),
                  pkbf(f1.x, f1.y), pkbf(f1.z, f1.w)};
    uint4v bq1 = {pkbf(f2.x, f2.y), pkbf(f2.z, f2.w),
                  pkbf(f3.x, f3.y), pkbf(f3.z, f3.w)};
    short8 bf0 = __builtin_bit_cast(short8, bq0);
    short8 bf1 = __builtin_bit_cast(short8, bq1);

    float ysum = 0.f;
#pragma unroll
    for (int t = 0; t < 8; ++t) {
      float4v acc = {0.f, 0.f, 0.f, 0.f};
      acc = __builtin_amdgcn_mfma_f32_16x16x32_bf16(afrag[t][0], bf0, acc, 0, 0, 0);
      acc = __builtin_amdgcn_mfma_f32_16x16x32_bf16(afrag[t][1], bf1, acc, 0, 0, 0);
#pragma unroll
      for (int r = 0; r < 4; ++r) {
        unsigned int u = bwreg[t][r];
        float b1v = __builtin_bit_cast(float, u & 0xFFFF0000u);
        float w2v = __builtin_bit_cast(float, u << 16);
        ysum = fmaf(fmaxf(acc[r] + b1v, 0.f), w2v, ysum);
      }
    }
    ysum += __shfl_xor(ysum, 16, 64);
    ysum += __shfl_xor(ysum, 32, 64);
    float y = fmaxf(ysum + b2f, 0.f);
    if (quad == 0) {
      float* yp = ydst + (size_t)f * y_fmul
                       + (size_t)(row_w0 + s * 16 + col) * y_rmul + y_cadd;
      *yp = y;                    // store sits between prefetch batches; the
    }                             // next iter's vmcnt(4) retires it.
  }
#undef ISSUE
}

// Kernel 3: transpose-combine. 32 rows x 32 f per block: coalesced y reads
// (f-major ws), LDS transpose, coalesced float2 writes of (X, y).
__global__ __launch_bounds__(256) void ContMlp_combine(
    const float* __restrict__ X, const float* __restrict__ yws,
    float* __restrict__ out) {
  __shared__ float yl[F_SZ][33];
  const int r0 = blockIdx.x * 32;
  const int t = threadIdx.x;
#pragma unroll
  for (int i = 0; i < 4; ++i) {
    int idx = t + 256 * i;
    int f = idx >> 5, r = idx & 31;
    yl[f][r] = yws[(size_t)f * B_SZ + r0 + r];
  }
  __syncthreads();
#pragma unroll
  for (int i = 0; i < 4; ++i) {
    int idx = t + 256 * i;
    int r = idx >> 5, f = idx & 31;
    float2 o2 = make_float2(X[(size_t)(r0 + r) * F_SZ + f], yl[f][r]);
    *(float2*)(out + (size_t)(r0 + r) * (2 * F_SZ) + 2 * f) = o2;
  }
}

// Fallback X-scatter for the no-workspace path.
__global__ __launch_bounds__(256) void ContMlp_xwrite(
    const float* __restrict__ X, float* __restrict__ out) {
  int idx = blockIdx.x * 256 + threadIdx.x;
  int r = idx >> 5, f = idx & 31;
  out[(size_t)r * (2 * F_SZ) + 2 * f] = X[idx];
}

extern "C" void kernel_launch(void* const* d_in, const int* in_sizes, int n_in,
                              void* d_out, int out_size, void* d_ws, size_t ws_size,
                              hipStream_t stream) {
  const float* X  = (const float*)d_in[0];
  const float* r_ = (const float*)d_in[1];
  const float* W1 = (const float*)d_in[2];
  const float* b1 = (const float*)d_in[3];
  const float* W2 = (const float*)d_in[4];
  const float* b2 = (const float*)d_in[5];
  float* out = (float*)d_out;

  const size_t w1t_bytes = (size_t)F_SZ * H_SZ * D_SZ * 2;   // 512 KB
  const size_t bw_off    = w1t_bytes;
  const size_t bw_bytes  = (size_t)F_SZ * H_SZ * 4;          // 16 KB
  const size_t y_off     = bw_off + bw_bytes;
  const size_t y_bytes   = (size_t)B_SZ * F_SZ * 4;          // 2 MB

  unsigned short* w1t = (unsigned short*)d_ws;
  unsigned int*   bw  = (unsigned int*)((char*)d_ws + bw_off);

  ContMlp_prep<<<F_SZ * 4, 256, 0, stream>>>(W1, b1, W2, w1t, bw);

  if (ws_size >= y_off + y_bytes) {
    float* yws = (float*)((char*)d_ws + y_off);
    ContMlp_main<<<64 * F_SZ, 128, 0, stream>>>(r_, w1t, bw, b2, yws,
                                                B_SZ, 1, 0);
    ContMlp_combine<<<B_SZ / 32, 256, 0, stream>>>(X, yws, out);
  } else {
    ContMlp_main<<<64 * F_SZ, 128, 0, stream>>>(r_, w1t, bw, b2, out,
                                                2, 2 * F_SZ, 1);
    ContMlp_xwrite<<<(B_SZ * F_SZ) / 256, 256, 0, stream>>>(X, out);
  }
}

// Round 8
// 214.229 us; speedup vs baseline: 1.0130x; 1.0130x over previous
//
#include <hip/hip_runtime.h>
#include <stdint.h>

// Problem constants (from reference): B=16384, F=32, D=64, H=2*D=128.
#define B_SZ 16384
#define F_SZ 32
#define D_SZ 64
#define H_SZ 128
#define RSTRIDE 72   // w1l LDS row stride in shorts (144 B) -> conflict-free A-frag reads

typedef __attribute__((ext_vector_type(8))) short  short8;   // 8 x bf16 MFMA frag
typedef __attribute__((ext_vector_type(4))) float  float4v;
typedef __attribute__((ext_vector_type(4))) unsigned int uint4v;

// round-half-up f32->bf16, pack (lo -> bits[15:0], hi -> bits[31:16])
__device__ __forceinline__ unsigned int pkbf(float lo, float hi) {
  unsigned int ulo = __builtin_bit_cast(unsigned int, lo) + 0x8000u;
  unsigned int uhi = __builtin_bit_cast(unsigned int, hi) + 0x8000u;
  return __builtin_amdgcn_perm(uhi, ulo, 0x07060302u);
}

// Kernel 1: W1 [F][D][H] f32 -> w1t [F][H][D] bf16 (A-fragment order), and
// pack {b1,w2} per h into one u32 (b1 hi16, w2 lo16).
__global__ __launch_bounds__(256) void ContMlp_prep(
    const float* __restrict__ W1, const float* __restrict__ b1,
    const float* __restrict__ W2, unsigned short* __restrict__ w1t,
    unsigned int* __restrict__ bw) {
  const int f  = blockIdx.x >> 2;
  const int hq = blockIdx.x & 3;
  const int h0 = hq * 32;
  const int t  = threadIdx.x;
  __shared__ float lds[D_SZ][33];
  const float* w1f = W1 + (size_t)f * (D_SZ * H_SZ);
#pragma unroll
  for (int i = 0; i < 8; ++i) {
    int idx = t + 256 * i;
    int d = idx >> 5, hh = idx & 31;
    lds[d][hh] = w1f[d * H_SZ + h0 + hh];
  }
  __syncthreads();
  unsigned short* o = w1t + (size_t)f * (H_SZ * D_SZ);
#pragma unroll
  for (int i = 0; i < 8; ++i) {
    int idx = t + 256 * i;
    int hh = idx >> 6, d = idx & 63;
    unsigned int u = __builtin_bit_cast(unsigned int, lds[d][hh]) + 0x8000u;
    o[(h0 + hh) * D_SZ + d] = (unsigned short)(u >> 16);
  }
  if (hq == 0 && t < H_SZ) {
    unsigned int ub = __builtin_bit_cast(unsigned int, b1[f * H_SZ + t]) + 0x8000u;
    unsigned int uw = __builtin_bit_cast(unsigned int, W2[f * H_SZ + t]) + 0x8000u;
    bw[f * H_SZ + t] = (ub & 0xFFFF0000u) | (uw >> 16);
  }
}

// Kernel 2: single-pass f32 main (R6 configuration — measured 213.2 us total,
// main ~25 us at ~5.3 TB/s, near the 21 us HBM floor for 128 MB of r_).
// Grid = 32 row-tiles x 32 f = 1024 blocks. Block = 4 waves x 128 rows;
// 8 subtiles of 16 rows per wave.
//
// r_ staging: __builtin_amdgcn_global_load_lds width=16 into a per-wave 4 KB
// LDS buffer — ZERO staging VGPRs (R2-R5: f32 staging in VGPRs spilled at the
// LDS-implied 64-VGPR budget). Chunk-major slot layout (slot = c*16 + r,
// 16B slots) -> conflict-free ds_read_b128 fragment reads.
// Per-subtile vmcnt(0) drain is covered by 16 waves/CU of TLP (R7's
// vmcnt(4) never-drain pipeline measured NEUTRAL-to-worse: 213.2 -> 217.0).
// LDS total ~35 KB -> 4 blocks/CU.
__global__ __launch_bounds__(256) void ContMlp_main(
    const float* __restrict__ r_,
    const unsigned short* __restrict__ w1t, const unsigned int* __restrict__ bw,
    const float* __restrict__ b2, float* __restrict__ ydst,
    int y_fmul, int y_rmul, int y_cadd) {
  const int f    = blockIdx.x & 31;
  const int tile = blockIdx.x >> 5;
  const int w    = threadIdx.x >> 6;
  const int l    = threadIdx.x & 63;
  const int col  = l & 15;
  const int quad = l >> 4;

  __shared__ unsigned short w1l[H_SZ * RSTRIDE];   // 18432 B
  __shared__ unsigned int   bwl[H_SZ];             // 512 B
  __shared__ float          rbuf[4][1024];         // 16384 B, 4 KB per wave

  {  // stage weights (once per block)
    const uint4v* src = (const uint4v*)(w1t + (size_t)f * (H_SZ * D_SZ));
#pragma unroll
    for (int i = 0; i < 4; ++i) {
      int ci = threadIdx.x + 256 * i;
      int h = ci >> 3, dc = ci & 7;
      *(uint4v*)(w1l + h * RSTRIDE + dc * 8) = src[ci];
    }
    if (threadIdx.x < H_SZ) bwl[threadIdx.x] = bw[f * H_SZ + threadIdx.x];
  }
  __syncthreads();
  const float b2f = b2[f];

  const int row_w0 = tile * 512 + w * 128;
  // lane's staging gather base: row (row_w0 + col), float offset quad*4
  const float* gl = r_ + (size_t)(row_w0 + col) * (F_SZ * D_SZ)
                       + f * D_SZ + quad * 4;
  float* rb = &rbuf[w][0];
  float yv[8];

#pragma unroll 1
  for (int s = 0; s < 8; ++s) {
    const float* gs = gl + (size_t)s * 16 * (F_SZ * D_SZ);
#pragma unroll
    for (int i = 0; i < 4; ++i) {
      __builtin_amdgcn_global_load_lds(
          (const __attribute__((address_space(1))) void*)(gs + i * 16),
          (__attribute__((address_space(3))) void*)(rb + i * 256),
          16, 0, 0);
    }
    __builtin_amdgcn_s_waitcnt(0x0F70);   // vmcnt(0), lgkm/exp untouched

    // fragment read (chunk-major): chunk c lives at floats (c*16+col)*4
    float4v f0 = *(const float4v*)(rb + (quad * 2) * 64 + col * 4);
    float4v f1 = *(const float4v*)(rb + (quad * 2 + 1) * 64 + col * 4);
    float4v f2 = *(const float4v*)(rb + (8 + quad * 2) * 64 + col * 4);
    float4v f3 = *(const float4v*)(rb + (9 + quad * 2) * 64 + col * 4);
    uint4v bq0 = {pkbf(f0.x, f0.y), pkbf(f0.z, f0.w),
                  pkbf(f1.x, f1.y), pkbf(f1.z, f1.w)};
    uint4v bq1 = {pkbf(f2.x, f2.y), pkbf(f2.z, f2.w),
                  pkbf(f3.x, f3.y), pkbf(f3.z, f3.w)};
    short8 bf0 = __builtin_bit_cast(short8, bq0);
    short8 bf1 = __builtin_bit_cast(short8, bq1);

    float ysum = 0.f;
#pragma unroll
    for (int t = 0; t < 8; ++t) {
      const unsigned short* wrow = w1l + (col + 16 * t) * RSTRIDE + quad * 8;
      short8 a0 = *(const short8*)(wrow);
      short8 a1 = *(const short8*)(wrow + 32);
      float4v acc = {0.f, 0.f, 0.f, 0.f};
      acc = __builtin_amdgcn_mfma_f32_16x16x32_bf16(a0, bf0, acc, 0, 0, 0);
      acc = __builtin_amdgcn_mfma_f32_16x16x32_bf16(a1, bf1, acc, 0, 0, 0);
      uint4v bwv = *(const uint4v*)(bwl + 16 * t + quad * 4);
#pragma unroll
      for (int r = 0; r < 4; ++r) {
        unsigned int u = bwv[r];
        float b1v = __builtin_bit_cast(float, u & 0xFFFF0000u);
        float w2v = __builtin_bit_cast(float, u << 16);
        ysum = fmaf(fmaxf(acc[r] + b1v, 0.f), w2v, ysum);
      }
    }
    ysum += __shfl_xor(ysum, 16, 64);
    ysum += __shfl_xor(ysum, 32, 64);
    yv[s] = fmaxf(ysum + b2f, 0.f);
  }

  if (quad == 0) {
#pragma unroll
    for (int s = 0; s < 8; ++s) {
      float* yp = ydst + (size_t)f * y_fmul
                       + (size_t)(row_w0 + s * 16 + col) * y_rmul + y_cadd;
      *yp = yv[s];
    }
  }
}

// Kernel 3: transpose-combine. 32 rows x 32 f per block: coalesced y reads
// (f-major ws), LDS transpose, coalesced float2 writes of (X, y).
__global__ __launch_bounds__(256) void ContMlp_combine(
    const float* __restrict__ X, const float* __restrict__ yws,
    float* __restrict__ out) {
  __shared__ float yl[F_SZ][33];
  const int r0 = blockIdx.x * 32;
  const int t = threadIdx.x;
#pragma unroll
  for (int i = 0; i < 4; ++i) {
    int idx = t + 256 * i;
    int f = idx >> 5, r = idx & 31;
    yl[f][r] = yws[(size_t)f * B_SZ + r0 + r];
  }
  __syncthreads();
#pragma unroll
  for (int i = 0; i < 4; ++i) {
    int idx = t + 256 * i;
    int r = idx >> 5, f = idx & 31;
    float2 o2 = make_float2(X[(size_t)(r0 + r) * F_SZ + f], yl[f][r]);
    *(float2*)(out + (size_t)(r0 + r) * (2 * F_SZ) + 2 * f) = o2;
  }
}

// Fallback X-scatter for the no-workspace path.
__global__ __launch_bounds__(256) void ContMlp_xwrite(
    const float* __restrict__ X, float* __restrict__ out) {
  int idx = blockIdx.x * 256 + threadIdx.x;
  int r = idx >> 5, f = idx & 31;
  out[(size_t)r * (2 * F_SZ) + 2 * f] = X[idx];
}

extern "C" void kernel_launch(void* const* d_in, const int* in_sizes, int n_in,
                              void* d_out, int out_size, void* d_ws, size_t ws_size,
                              hipStream_t stream) {
  const float* X  = (const float*)d_in[0];
  const float* r_ = (const float*)d_in[1];
  const float* W1 = (const float*)d_in[2];
  const float* b1 = (const float*)d_in[3];
  const float* W2 = (const float*)d_in[4];
  const float* b2 = (const float*)d_in[5];
  float* out = (float*)d_out;

  const size_t w1t_bytes = (size_t)F_SZ * H_SZ * D_SZ * 2;   // 512 KB
  const size_t bw_off    = w1t_bytes;
  const size_t bw_bytes  = (size_t)F_SZ * H_SZ * 4;          // 16 KB
  const size_t y_off     = bw_off + bw_bytes;
  const size_t y_bytes   = (size_t)B_SZ * F_SZ * 4;          // 2 MB

  unsigned short* w1t = (unsigned short*)d_ws;
  unsigned int*   bw  = (unsigned int*)((char*)d_ws + bw_off);

  ContMlp_prep<<<F_SZ * 4, 256, 0, stream>>>(W1, b1, W2, w1t, bw);

  if (ws_size >= y_off + y_bytes) {
    float* yws = (float*)((char*)d_ws + y_off);
    ContMlp_main<<<32 * F_SZ, 256, 0, stream>>>(r_, w1t, bw, b2, yws,
                                                B_SZ, 1, 0);
    ContMlp_combine<<<B_SZ / 32, 256, 0, stream>>>(X, yws, out);
  } else {
    ContMlp_main<<<32 * F_SZ, 256, 0, stream>>>(r_, w1t, bw, b2, out,
                                                2, 2 * F_SZ, 1);
    ContMlp_xwrite<<<(B_SZ * F_SZ) / 256, 256, 0, stream>>>(X, out);
  }
}